// Round 7
// baseline (51.095 us; speedup 1.0000x reference)
//
#include <hip/hip_runtime.h>
#include <math.h>
#include <float.h>

#define ROWS 1000000
#define NTHR 256
#define NBLK_L 3907                  // ceil(1e6 / 256)  -> one row per thread
#define NBLK_B 977                   // ceil(250000 float4 / 256)
#define NEG_BIG (-3.0e38f)

// scalar line-touch warm: threads wt=0..127 touch every 16th float (64B line)
__device__ __forceinline__ float warmS(const float* p, int n, int wt) {
    float a = 0.f;
    for (int i = wt * 16; i < n; i += 128 * 16) a += p[i];
    return a;
}

// ---------------------------------------------------------------------------
// K0: front (1 block x 256). Threads 0-127: round-1-proven chain logic.
// Threads 128-255: parallel L2 warm of all front weights/biases so every
// chain phase hits L2 instead of HBM. Writes h_new to ws[0:32] + small outs.
// ---------------------------------------------------------------------------
__global__ __launch_bounds__(256) void front_kernel(
    const int* __restrict__ x, const float* __restrict__ hidden, const int* __restrict__ pos,
    const float* __restrict__ loc_emb, const float* __restrict__ arr_emb,
    const float* __restrict__ dur_emb, const float* __restrict__ pos_emb,
    const float* __restrict__ f1rW1, const float* __restrict__ f1rb1,
    const float* __restrict__ f1rW2, const float* __restrict__ f1rb2,
    const float* __restrict__ f1W,   const float* __restrict__ f1b,
    const float* __restrict__ f2rW1, const float* __restrict__ f2rb1,
    const float* __restrict__ f2rW2, const float* __restrict__ f2rb2,
    const float* __restrict__ f2W,   const float* __restrict__ f2b,
    const float* __restrict__ f3rW1, const float* __restrict__ f3rb1,
    const float* __restrict__ f3rW2, const float* __restrict__ f3rb2,
    const float* __restrict__ f3W,   const float* __restrict__ f3b,
    const float* __restrict__ ln_g,  const float* __restrict__ ln_b,
    const float* __restrict__ ode_W, const float* __restrict__ ode_b,
    const float* __restrict__ oW1,   const float* __restrict__ ob1,
    const float* __restrict__ oW2,   const float* __restrict__ ob2,
    const float* __restrict__ fc5_W, const float* __restrict__ fc5_b,
    const float* __restrict__ fc6_W, const float* __restrict__ fc6_b,
    const float* __restrict__ gWih,  const float* __restrict__ gbih,
    const float* __restrict__ gWhh,  const float* __restrict__ gbhh,
    float* __restrict__ out, float* __restrict__ ws)
{
    __shared__ float e[3][16], tr[3][16], h1[3][16];
    __shared__ float praw[15], pnorm[15];
    __shared__ float ode0[32], odt[32], hvec[32], hnew[32], pe[32];
    __shared__ float gi[96], gh[96];
    __shared__ float a5[24], a6[24];
    __shared__ float red[4];

    const int t = threadIdx.x;

    // ---- warm (threads 128-255): all independent scalar loads, one wait ----
    if (t >= 128) {
        const int wt = t - 128;
        float a = warmS(gWih, 1440, wt) + warmS(gbih, 96, wt)
                + warmS(gWhh, 3072, wt) + warmS(gbhh, 96, wt)
                + warmS(oW1, 1024, wt)  + warmS(ob1, 32, wt)
                + warmS(oW2, 1024, wt)  + warmS(ob2, 32, wt)
                + warmS(ode_W, 160, wt) + warmS(ode_b, 32, wt)
                + warmS(fc5_W, 768, wt) + warmS(fc5_b, 24, wt)
                + warmS(fc6_W, 768, wt) + warmS(fc6_b, 24, wt)
                + warmS(f1rW1, 512, wt) + warmS(f1rb1, 32, wt)
                + warmS(f1rW2, 512, wt) + warmS(f1rb2, 32, wt)
                + warmS(f2rW1, 512, wt) + warmS(f2rb1, 32, wt)
                + warmS(f2rW2, 512, wt) + warmS(f2rb2, 32, wt)
                + warmS(f3rW1, 512, wt) + warmS(f3rb1, 32, wt)
                + warmS(f3rW2, 512, wt) + warmS(f3rb2, 32, wt)
                + warmS(f1W, 80, wt) + warmS(f1b, 5, wt)
                + warmS(f2W, 80, wt) + warmS(f2b, 5, wt)
                + warmS(f3W, 80, wt) + warmS(f3b, 5, wt)
                + warmS(ln_g, 15, wt) + warmS(ln_b, 15, wt)
                + warmS(pos_emb, 320, wt) + warmS(hidden, 32, wt);
        asm volatile("" :: "v"(a));
    }

    if (t < 48) {
        int c = t >> 4, j = t & 15;
        const float* emb = (c == 0) ? (loc_emb + (size_t)x[0] * 16)
                         : (c == 1) ? (arr_emb + (size_t)x[1] * 16)
                                    : (dur_emb + (size_t)x[2] * 16);
        e[c][j] = emb[j];
    }
    if (t < 32) pe[t] = pos_emb[pos[0] * 32 + t];
    __syncthreads();

    for (int i = 0; i < 2; ++i) {
        if (t < 48) { int c = t >> 4, j = t & 15; tr[c][j] = fmaxf(e[c][j], 0.f); }
        __syncthreads();
        if (t < 48) {
            int c = t >> 4, j = t & 15;
            const float* W1 = ((c == 0) ? f1rW1 : (c == 1) ? f2rW1 : f3rW1) + i * 256 + j * 16;
            const float* b1 = ((c == 0) ? f1rb1 : (c == 1) ? f2rb1 : f3rb1) + i * 16;
            float a = b1[j];
            #pragma unroll
            for (int k = 0; k < 16; ++k) a += W1[k] * tr[c][k];
            h1[c][j] = fmaxf(a, 0.f);
        }
        __syncthreads();
        if (t < 48) {
            int c = t >> 4, j = t & 15;
            const float* W2 = ((c == 0) ? f1rW2 : (c == 1) ? f2rW2 : f3rW2) + i * 256 + j * 16;
            const float* b2 = ((c == 0) ? f1rb2 : (c == 1) ? f2rb2 : f3rb2) + i * 16;
            float a = b2[j];
            #pragma unroll
            for (int k = 0; k < 16; ++k) a += W2[k] * h1[c][k];
            e[c][j] += 0.3f * a;
        }
        __syncthreads();
    }

    if (t < 15) {
        int c = t / 5, q = t % 5;
        const float* W = ((c == 0) ? f1W : (c == 1) ? f2W : f3W) + q * 16;
        const float* b = ((c == 0) ? f1b : (c == 1) ? f2b : f3b);
        float a = b[q];
        #pragma unroll
        for (int k = 0; k < 16; ++k) a += W[k] * e[c][k];
        praw[t] = a;
    }
    __syncthreads();

    if (t == 0) {
        float mu = 0.f;
        for (int k = 0; k < 15; ++k) mu += praw[k];
        mu *= (1.f / 15.f);
        float var = 0.f;
        for (int k = 0; k < 15; ++k) { float d = praw[k] - mu; var += d * d; }
        var *= (1.f / 15.f);
        red[0] = mu;
        red[1] = rsqrtf(var + 1e-5f);
    }
    __syncthreads();
    if (t < 15) pnorm[t] = (praw[t] - red[0]) * red[1] * ln_g[t] + ln_b[t];
    if (t < 32) {
        float a = ode_b[t];
        const float* W = ode_W + t * 5;
        #pragma unroll
        for (int k = 0; k < 5; ++k) a += W[k] * praw[10 + k];
        ode0[t] = a;
    }
    __syncthreads();
    if (t < 32) {
        float a = ob1[t];
        const float* W = oW1 + t * 32;
        #pragma unroll
        for (int k = 0; k < 32; ++k) a += W[k] * fmaxf(ode0[k], 0.f);
        odt[t] = fmaxf(a, 0.f);
    }
    __syncthreads();
    if (t < 32) {
        float a = ob2[t];
        const float* W = oW2 + t * 32;
        #pragma unroll
        for (int k = 0; k < 32; ++k) a += W[k] * odt[k];
        hvec[t] = hidden[t] + ode0[t] + 0.3f * a;
    }
    __syncthreads();
    if (t < 96) {
        float a = gbih[t];
        const float* W = gWih + t * 15;
        #pragma unroll
        for (int k = 0; k < 15; ++k) a += W[k] * pnorm[k];
        gi[t] = a;
        float c2 = gbhh[t];
        const float* V = gWhh + t * 32;
        #pragma unroll
        for (int k = 0; k < 32; ++k) c2 += V[k] * hvec[k];
        gh[t] = c2;
    }
    __syncthreads();
    if (t < 32) {
        float r = 1.f / (1.f + expf(-(gi[t] + gh[t])));
        float z = 1.f / (1.f + expf(-(gi[32 + t] + gh[32 + t])));
        float n = tanhf(gi[64 + t] + r * gh[64 + t]);
        float hn = (1.f - z) * n + z * hvec[t];
        hnew[t] = hn;
        ws[t] = hn;
        out[ROWS + 48 + t] = hn;
    }
    __syncthreads();
    if (t < 24) {
        float a = fc5_b[t];
        const float* W = fc5_W + t * 32;
        #pragma unroll
        for (int k = 0; k < 32; ++k) a += W[k] * (hnew[k] + pe[k]);
        a5[t] = a;
        float b = fc6_b[t];
        const float* V = fc6_W + t * 32;
        #pragma unroll
        for (int k = 0; k < 32; ++k) b += V[k] * hnew[k];
        a6[t] = b;
    }
    __syncthreads();
    if (t == 0) {
        float m = -INFINITY;
        for (int k = 0; k < 24; ++k) m = fmaxf(m, a5[k]);
        float s = 0.f;
        for (int k = 0; k < 24; ++k) s += expf(a5[k] - m);
        red[2] = m + logf(s);
        m = -INFINITY;
        for (int k = 0; k < 24; ++k) m = fmaxf(m, a6[k]);
        s = 0.f;
        for (int k = 0; k < 24; ++k) s += expf(a6[k] - m);
        red[3] = m + logf(s);
    }
    __syncthreads();
    if (t < 24) {
        out[ROWS + t]      = a5[t] - red[2];
        out[ROWS + 24 + t] = a6[t] - red[3];
    }
}

// online-softmax pair merge via wave shuffle, 6 xor steps over 64 lanes
__device__ __forceinline__ void wave_merge(float& m, float& s) {
    #pragma unroll
    for (int off = 1; off < 64; off <<= 1) {
        float m2 = __shfl_xor(m, off);
        float s2 = __shfl_xor(s, off);
        float M  = fmaxf(m, m2);
        s = s * __expf(m - M) + s2 * __expf(m2 - M);
        m = M;
    }
}

// ---------------------------------------------------------------------------
// K1: one row per thread. 8 independent float4 loads -> 32 FMA -> coalesced
// store. Wave shuffle reduce (1 barrier) -> per-block (m,s) partial.
// ---------------------------------------------------------------------------
__global__ __launch_bounds__(NTHR) void logits_kernel(
    const float* __restrict__ W, const float* __restrict__ b,
    const float* __restrict__ ws_h, float* __restrict__ out,
    float2* __restrict__ partials)
{
    __shared__ float hs[32];
    __shared__ float2 wred[4];
    if (threadIdx.x < 32) hs[threadIdx.x] = ws_h[threadIdx.x];
    __syncthreads();

    const int t = threadIdx.x;
    const int r = blockIdx.x * NTHR + t;

    float m = NEG_BIG, s = 0.f;
    if (r < ROWS) {
        const float4* W4 = (const float4*)W;
        float4 w[8];
        #pragma unroll
        for (int j = 0; j < 8; ++j) w[j] = W4[(size_t)r * 8 + j];
        float acc = b[r];
        #pragma unroll
        for (int j = 0; j < 8; ++j)
            acc += w[j].x * hs[4*j] + w[j].y * hs[4*j+1]
                 + w[j].z * hs[4*j+2] + w[j].w * hs[4*j+3];
        out[r] = acc;
        m = acc; s = 1.f;
    }

    wave_merge(m, s);
    if ((t & 63) == 0) wred[t >> 6] = make_float2(m, s);
    __syncthreads();
    if (t == 0) {
        float fm = wred[0].x, fs = wred[0].y;
        #pragma unroll
        for (int i = 1; i < 4; ++i) {
            float m2 = wred[i].x, s2 = wred[i].y;
            float M  = fmaxf(fm, m2);
            fs = fs * __expf(fm - M) + s2 * __expf(m2 - M);
            fm = M;
        }
        partials[blockIdx.x] = make_float2(fm, fs);
    }
}

// ---------------------------------------------------------------------------
// K2: every block redundantly reduces the 3907 partials -> lse, then
// subtracts over its float4 slice of out.
// ---------------------------------------------------------------------------
__global__ __launch_bounds__(256) void finalize_kernel(
    const float2* __restrict__ partials, float* __restrict__ out)
{
    __shared__ float2 wred[4];
    __shared__ float lse_sh;
    const int t = threadIdx.x;

    float fm = NEG_BIG, fs = 0.f;
    for (int i = t; i < NBLK_L; i += 256) {
        float2 p2 = partials[i];
        float M = fmaxf(fm, p2.x);
        fs = fs * __expf(fm - M) + p2.y * __expf(p2.x - M);
        fm = M;
    }
    wave_merge(fm, fs);
    if ((t & 63) == 0) wred[t >> 6] = make_float2(fm, fs);
    __syncthreads();
    if (t == 0) {
        float m = wred[0].x, s = wred[0].y;
        #pragma unroll
        for (int i = 1; i < 4; ++i) {
            float m2 = wred[i].x, s2 = wred[i].y;
            float M  = fmaxf(m, m2);
            s = s * __expf(m - M) + s2 * __expf(m2 - M);
            m = M;
        }
        lse_sh = m + logf(s);
    }
    __syncthreads();
    const float lse = lse_sh;

    const int idx = blockIdx.x * 256 + t;
    if (idx < ROWS / 4) {
        float4* o4 = (float4*)out;
        float4 v = o4[idx];
        v.x -= lse; v.y -= lse; v.z -= lse; v.w -= lse;
        o4[idx] = v;
    }
}

extern "C" void kernel_launch(void* const* d_in, const int* in_sizes, int n_in,
                              void* d_out, int out_size, void* d_ws, size_t ws_size,
                              hipStream_t stream) {
    const int*   x       = (const int*)  d_in[0];
    const float* hidden  = (const float*)d_in[1];
    const int*   pos     = (const int*)  d_in[2];
    const float* loc_emb = (const float*)d_in[3];
    const float* arr_emb = (const float*)d_in[4];
    const float* dur_emb = (const float*)d_in[5];
    const float* pos_emb = (const float*)d_in[6];
    const float* f1rW1 = (const float*)d_in[7];
    const float* f1rb1 = (const float*)d_in[8];
    const float* f1rW2 = (const float*)d_in[9];
    const float* f1rb2 = (const float*)d_in[10];
    const float* f1W   = (const float*)d_in[11];
    const float* f1b   = (const float*)d_in[12];
    const float* f2rW1 = (const float*)d_in[13];
    const float* f2rb1 = (const float*)d_in[14];
    const float* f2rW2 = (const float*)d_in[15];
    const float* f2rb2 = (const float*)d_in[16];
    const float* f2W   = (const float*)d_in[17];
    const float* f2b   = (const float*)d_in[18];
    const float* f3rW1 = (const float*)d_in[19];
    const float* f3rb1 = (const float*)d_in[20];
    const float* f3rW2 = (const float*)d_in[21];
    const float* f3rb2 = (const float*)d_in[22];
    const float* f3W   = (const float*)d_in[23];
    const float* f3b   = (const float*)d_in[24];
    const float* ln_g  = (const float*)d_in[25];
    const float* ln_b  = (const float*)d_in[26];
    const float* ode_W = (const float*)d_in[27];
    const float* ode_b = (const float*)d_in[28];
    const float* oW1   = (const float*)d_in[29];
    const float* ob1   = (const float*)d_in[30];
    const float* oW2   = (const float*)d_in[31];
    const float* ob2   = (const float*)d_in[32];
    const float* fc4_W = (const float*)d_in[33];
    const float* fc4_b = (const float*)d_in[34];
    const float* fc5_W = (const float*)d_in[35];
    const float* fc5_b = (const float*)d_in[36];
    const float* fc6_W = (const float*)d_in[37];
    const float* fc6_b = (const float*)d_in[38];
    const float* gWih  = (const float*)d_in[39];
    const float* gbih  = (const float*)d_in[40];
    const float* gWhh  = (const float*)d_in[41];
    const float* gbhh  = (const float*)d_in[42];

    float* out = (float*)d_out;
    float* wsf = (float*)d_ws;
    // ws layout: [0:32) h_new ; [64 : 64+2*NBLK_L) partials (float2-aligned)
    float*  ws_h        = wsf;
    float2* ws_partials = (float2*)(wsf + 64);

    front_kernel<<<1, 256, 0, stream>>>(
        x, hidden, pos, loc_emb, arr_emb, dur_emb, pos_emb,
        f1rW1, f1rb1, f1rW2, f1rb2, f1W, f1b,
        f2rW1, f2rb1, f2rW2, f2rb2, f2W, f2b,
        f3rW1, f3rb1, f3rW2, f3rb2, f3W, f3b,
        ln_g, ln_b, ode_W, ode_b, oW1, ob1, oW2, ob2,
        fc5_W, fc5_b, fc6_W, fc6_b, gWih, gbih, gWhh, gbhh,
        out, ws_h);

    logits_kernel<<<NBLK_L, NTHR, 0, stream>>>(
        fc4_W, fc4_b, ws_h, out, ws_partials);

    finalize_kernel<<<NBLK_B, 256, 0, stream>>>(ws_partials, out);
}

// Round 8
// 46.974 us; speedup vs baseline: 1.0877x; 1.0877x over previous
//
#include <hip/hip_runtime.h>
#include <math.h>
#include <float.h>

#define ROWS 1000000
#define NTHR 256
#define NBLK_L 3907                  // ceil(15625 waves / 4 waves-per-block)
#define NWAVE_VALID 15625            // 15625 waves x 64 rows = exactly 1M rows
#define NBLK_B 977                   // ceil(250000 float4 / 256)
#define NEG_BIG (-3.0e38f)

// ---------------------------------------------------------------------------
// K0: front (1 block x 128) — byte-identical to the round-6 PASSING version.
// Writes h_new to ws[0:32] and the small outputs.
// ---------------------------------------------------------------------------
__global__ __launch_bounds__(128) void front_kernel(
    const int* __restrict__ x, const float* __restrict__ hidden, const int* __restrict__ pos,
    const float* __restrict__ loc_emb, const float* __restrict__ arr_emb,
    const float* __restrict__ dur_emb, const float* __restrict__ pos_emb,
    const float* __restrict__ f1rW1, const float* __restrict__ f1rb1,
    const float* __restrict__ f1rW2, const float* __restrict__ f1rb2,
    const float* __restrict__ f1W,   const float* __restrict__ f1b,
    const float* __restrict__ f2rW1, const float* __restrict__ f2rb1,
    const float* __restrict__ f2rW2, const float* __restrict__ f2rb2,
    const float* __restrict__ f2W,   const float* __restrict__ f2b,
    const float* __restrict__ f3rW1, const float* __restrict__ f3rb1,
    const float* __restrict__ f3rW2, const float* __restrict__ f3rb2,
    const float* __restrict__ f3W,   const float* __restrict__ f3b,
    const float* __restrict__ ln_g,  const float* __restrict__ ln_b,
    const float* __restrict__ ode_W, const float* __restrict__ ode_b,
    const float* __restrict__ oW1,   const float* __restrict__ ob1,
    const float* __restrict__ oW2,   const float* __restrict__ ob2,
    const float* __restrict__ fc5_W, const float* __restrict__ fc5_b,
    const float* __restrict__ fc6_W, const float* __restrict__ fc6_b,
    const float* __restrict__ gWih,  const float* __restrict__ gbih,
    const float* __restrict__ gWhh,  const float* __restrict__ gbhh,
    float* __restrict__ out, float* __restrict__ ws)
{
    __shared__ float e[3][16], tr[3][16], h1[3][16];
    __shared__ float praw[15], pnorm[15];
    __shared__ float ode0[32], odt[32], hvec[32], hnew[32], pe[32];
    __shared__ float gi[96], gh[96];
    __shared__ float a5[24], a6[24];
    __shared__ float red[4];

    const int t = threadIdx.x;

    if (t < 48) {
        int c = t >> 4, j = t & 15;
        const float* emb = (c == 0) ? (loc_emb + (size_t)x[0] * 16)
                         : (c == 1) ? (arr_emb + (size_t)x[1] * 16)
                                    : (dur_emb + (size_t)x[2] * 16);
        e[c][j] = emb[j];
    }
    if (t < 32) pe[t] = pos_emb[pos[0] * 32 + t];
    __syncthreads();

    for (int i = 0; i < 2; ++i) {
        if (t < 48) { int c = t >> 4, j = t & 15; tr[c][j] = fmaxf(e[c][j], 0.f); }
        __syncthreads();
        if (t < 48) {
            int c = t >> 4, j = t & 15;
            const float* W1 = ((c == 0) ? f1rW1 : (c == 1) ? f2rW1 : f3rW1) + i * 256 + j * 16;
            const float* b1 = ((c == 0) ? f1rb1 : (c == 1) ? f2rb1 : f3rb1) + i * 16;
            float a = b1[j];
            #pragma unroll
            for (int k = 0; k < 16; ++k) a += W1[k] * tr[c][k];
            h1[c][j] = fmaxf(a, 0.f);
        }
        __syncthreads();
        if (t < 48) {
            int c = t >> 4, j = t & 15;
            const float* W2 = ((c == 0) ? f1rW2 : (c == 1) ? f2rW2 : f3rW2) + i * 256 + j * 16;
            const float* b2 = ((c == 0) ? f1rb2 : (c == 1) ? f2rb2 : f3rb2) + i * 16;
            float a = b2[j];
            #pragma unroll
            for (int k = 0; k < 16; ++k) a += W2[k] * h1[c][k];
            e[c][j] += 0.3f * a;
        }
        __syncthreads();
    }

    if (t < 15) {
        int c = t / 5, q = t % 5;
        const float* W = ((c == 0) ? f1W : (c == 1) ? f2W : f3W) + q * 16;
        const float* b = ((c == 0) ? f1b : (c == 1) ? f2b : f3b);
        float a = b[q];
        #pragma unroll
        for (int k = 0; k < 16; ++k) a += W[k] * e[c][k];
        praw[t] = a;
    }
    __syncthreads();

    if (t == 0) {
        float mu = 0.f;
        for (int k = 0; k < 15; ++k) mu += praw[k];
        mu *= (1.f / 15.f);
        float var = 0.f;
        for (int k = 0; k < 15; ++k) { float d = praw[k] - mu; var += d * d; }
        var *= (1.f / 15.f);
        red[0] = mu;
        red[1] = rsqrtf(var + 1e-5f);
    }
    __syncthreads();
    if (t < 15) pnorm[t] = (praw[t] - red[0]) * red[1] * ln_g[t] + ln_b[t];
    if (t < 32) {
        float a = ode_b[t];
        const float* W = ode_W + t * 5;
        #pragma unroll
        for (int k = 0; k < 5; ++k) a += W[k] * praw[10 + k];
        ode0[t] = a;
    }
    __syncthreads();
    if (t < 32) {
        float a = ob1[t];
        const float* W = oW1 + t * 32;
        #pragma unroll
        for (int k = 0; k < 32; ++k) a += W[k] * fmaxf(ode0[k], 0.f);
        odt[t] = fmaxf(a, 0.f);
    }
    __syncthreads();
    if (t < 32) {
        float a = ob2[t];
        const float* W = oW2 + t * 32;
        #pragma unroll
        for (int k = 0; k < 32; ++k) a += W[k] * odt[k];
        hvec[t] = hidden[t] + ode0[t] + 0.3f * a;
    }
    __syncthreads();
    if (t < 96) {
        float a = gbih[t];
        const float* W = gWih + t * 15;
        #pragma unroll
        for (int k = 0; k < 15; ++k) a += W[k] * pnorm[k];
        gi[t] = a;
        float c2 = gbhh[t];
        const float* V = gWhh + t * 32;
        #pragma unroll
        for (int k = 0; k < 32; ++k) c2 += V[k] * hvec[k];
        gh[t] = c2;
    }
    __syncthreads();
    if (t < 32) {
        float r = 1.f / (1.f + expf(-(gi[t] + gh[t])));
        float z = 1.f / (1.f + expf(-(gi[32 + t] + gh[32 + t])));
        float n = tanhf(gi[64 + t] + r * gh[64 + t]);
        float hn = (1.f - z) * n + z * hvec[t];
        hnew[t] = hn;
        ws[t] = hn;
        out[ROWS + 48 + t] = hn;
    }
    __syncthreads();
    if (t < 24) {
        float a = fc5_b[t];
        const float* W = fc5_W + t * 32;
        #pragma unroll
        for (int k = 0; k < 32; ++k) a += W[k] * (hnew[k] + pe[k]);
        a5[t] = a;
        float b = fc6_b[t];
        const float* V = fc6_W + t * 32;
        #pragma unroll
        for (int k = 0; k < 32; ++k) b += V[k] * hnew[k];
        a6[t] = b;
    }
    __syncthreads();
    if (t == 0) {
        float m = -INFINITY;
        for (int k = 0; k < 24; ++k) m = fmaxf(m, a5[k]);
        float s = 0.f;
        for (int k = 0; k < 24; ++k) s += expf(a5[k] - m);
        red[2] = m + logf(s);
        m = -INFINITY;
        for (int k = 0; k < 24; ++k) m = fmaxf(m, a6[k]);
        s = 0.f;
        for (int k = 0; k < 24; ++k) s += expf(a6[k] - m);
        red[3] = m + logf(s);
    }
    __syncthreads();
    if (t < 24) {
        out[ROWS + t]      = a5[t] - red[2];
        out[ROWS + 24 + t] = a6[t] - red[3];
    }
}

// ---------------------------------------------------------------------------
// K1: wave-contiguous GEMV. Wave wv owns rows [wv*64, wv*64+64). Iteration it
// loads W4[wv*512 + it*64 + lane] -> one contiguous 1 KiB segment per load
// instruction. 8 independent loads/thread in flight, then 8 independent
// 3-step shfl_xor group reductions. Lane-group (l>>3) = one row; j==0 lanes
// carry the (m, sumexp) contribution (each row counted once).
// ---------------------------------------------------------------------------
__global__ __launch_bounds__(NTHR) void logits_kernel(
    const float* __restrict__ W, const float* __restrict__ b,
    const float* __restrict__ ws_h, float* __restrict__ out,
    float2* __restrict__ partials)
{
    __shared__ float4 hs4[8];
    const int t = threadIdx.x;
    if (t < 8) hs4[t] = ((const float4*)ws_h)[t];
    __syncthreads();

    const int l  = t & 63;
    const int wv = blockIdx.x * (NTHR / 64) + (t >> 6);   // global wave id
    const int j  = l & 7;                                  // chunk within row
    const int g  = l >> 3;                                 // row within group

    float m = NEG_BIG, s = 0.f;
    if (wv < NWAVE_VALID) {
        const float4 h4 = hs4[j];
        const float4* W4 = (const float4*)W;
        const size_t base = (size_t)wv * 512 + l;

        float4 w[8];
        #pragma unroll
        for (int it = 0; it < 8; ++it) w[it] = W4[base + it * 64];

        const int rowb = wv * 64 + g;
        float lg[8];
        #pragma unroll
        for (int it = 0; it < 8; ++it) {
            float pp = w[it].x * h4.x + w[it].y * h4.y
                     + w[it].z * h4.z + w[it].w * h4.w;
            pp += __shfl_xor(pp, 1);
            pp += __shfl_xor(pp, 2);
            pp += __shfl_xor(pp, 4);
            lg[it] = pp + b[rowb + it * 8];
            if (j == 0) out[rowb + it * 8] = lg[it];
        }
        if (j == 0) {
            m = lg[0];
            #pragma unroll
            for (int it = 1; it < 8; ++it) m = fmaxf(m, lg[it]);
            #pragma unroll
            for (int it = 0; it < 8; ++it) s += __expf(lg[it] - m);
        }
    }

    // block LDS-tree reduce (m,s) -> partials[blockIdx.x]  (round-6 proven)
    __shared__ float sm[NTHR], ss[NTHR];
    sm[t] = m; ss[t] = s;
    __syncthreads();
    for (int off = NTHR / 2; off > 0; off >>= 1) {
        if (t < off) {
            float m2 = sm[t + off], s2 = ss[t + off];
            float M  = fmaxf(sm[t], m2);
            ss[t] = ss[t] * __expf(sm[t] - M) + s2 * __expf(m2 - M);
            sm[t] = M;
        }
        __syncthreads();
    }
    if (t == 0) partials[blockIdx.x] = make_float2(sm[0], ss[0]);
}

// ---------------------------------------------------------------------------
// K2: every block redundantly reduces the 3907 partials -> lse, then
// subtracts over its float4 slice of out. (round-6 proven)
// ---------------------------------------------------------------------------
__global__ __launch_bounds__(256) void finalize_kernel(
    const float2* __restrict__ partials, float* __restrict__ out)
{
    __shared__ float sm[256], ss[256];
    __shared__ float lse_sh;
    const int t = threadIdx.x;

    float fm = NEG_BIG, fs = 0.f;
    for (int i = t; i < NBLK_L; i += 256) {
        float2 p2 = partials[i];
        float M = fmaxf(fm, p2.x);
        fs = fs * __expf(fm - M) + p2.y * __expf(p2.x - M);
        fm = M;
    }
    sm[t] = fm; ss[t] = fs;
    __syncthreads();
    for (int off = 128; off > 0; off >>= 1) {
        if (t < off) {
            float m2 = sm[t + off], s2 = ss[t + off];
            float M  = fmaxf(sm[t], m2);
            ss[t] = ss[t] * __expf(sm[t] - M) + s2 * __expf(m2 - M);
            sm[t] = M;
        }
        __syncthreads();
    }
    if (t == 0) lse_sh = sm[0] + logf(ss[0]);
    __syncthreads();
    const float lse = lse_sh;

    const int idx = blockIdx.x * 256 + t;
    if (idx < ROWS / 4) {
        float4* o4 = (float4*)out;
        float4 v = o4[idx];
        v.x -= lse; v.y -= lse; v.z -= lse; v.w -= lse;
        o4[idx] = v;
    }
}

extern "C" void kernel_launch(void* const* d_in, const int* in_sizes, int n_in,
                              void* d_out, int out_size, void* d_ws, size_t ws_size,
                              hipStream_t stream) {
    const int*   x       = (const int*)  d_in[0];
    const float* hidden  = (const float*)d_in[1];
    const int*   pos     = (const int*)  d_in[2];
    const float* loc_emb = (const float*)d_in[3];
    const float* arr_emb = (const float*)d_in[4];
    const float* dur_emb = (const float*)d_in[5];
    const float* pos_emb = (const float*)d_in[6];
    const float* f1rW1 = (const float*)d_in[7];
    const float* f1rb1 = (const float*)d_in[8];
    const float* f1rW2 = (const float*)d_in[9];
    const float* f1rb2 = (const float*)d_in[10];
    const float* f1W   = (const float*)d_in[11];
    const float* f1b   = (const float*)d_in[12];
    const float* f2rW1 = (const float*)d_in[13];
    const float* f2rb1 = (const float*)d_in[14];
    const float* f2rW2 = (const float*)d_in[15];
    const float* f2rb2 = (const float*)d_in[16];
    const float* f2W   = (const float*)d_in[17];
    const float* f2b   = (const float*)d_in[18];
    const float* f3rW1 = (const float*)d_in[19];
    const float* f3rb1 = (const float*)d_in[20];
    const float* f3rW2 = (const float*)d_in[21];
    const float* f3rb2 = (const float*)d_in[22];
    const float* f3W   = (const float*)d_in[23];
    const float* f3b   = (const float*)d_in[24];
    const float* ln_g  = (const float*)d_in[25];
    const float* ln_b  = (const float*)d_in[26];
    const float* ode_W = (const float*)d_in[27];
    const float* ode_b = (const float*)d_in[28];
    const float* oW1   = (const float*)d_in[29];
    const float* ob1   = (const float*)d_in[30];
    const float* oW2   = (const float*)d_in[31];
    const float* ob2   = (const float*)d_in[32];
    const float* fc4_W = (const float*)d_in[33];
    const float* fc4_b = (const float*)d_in[34];
    const float* fc5_W = (const float*)d_in[35];
    const float* fc5_b = (const float*)d_in[36];
    const float* fc6_W = (const float*)d_in[37];
    const float* fc6_b = (const float*)d_in[38];
    const float* gWih  = (const float*)d_in[39];
    const float* gbih  = (const float*)d_in[40];
    const float* gWhh  = (const float*)d_in[41];
    const float* gbhh  = (const float*)d_in[42];

    float* out = (float*)d_out;
    float* wsf = (float*)d_ws;
    // ws layout: [0:32) h_new ; [64 : 64+2*NBLK_L) partials (float2-aligned)
    float*  ws_h        = wsf;
    float2* ws_partials = (float2*)(wsf + 64);

    front_kernel<<<1, 128, 0, stream>>>(
        x, hidden, pos, loc_emb, arr_emb, dur_emb, pos_emb,
        f1rW1, f1rb1, f1rW2, f1rb2, f1W, f1b,
        f2rW1, f2rb1, f2rW2, f2rb2, f2W, f2b,
        f3rW1, f3rb1, f3rW2, f3rb2, f3W, f3b,
        ln_g, ln_b, ode_W, ode_b, oW1, ob1, oW2, ob2,
        fc5_W, fc5_b, fc6_W, fc6_b, gWih, gbih, gWhh, gbhh,
        out, ws_h);

    logits_kernel<<<NBLK_L, NTHR, 0, stream>>>(
        fc4_W, fc4_b, ws_h, out, ws_partials);

    finalize_kernel<<<NBLK_B, 256, 0, stream>>>(ws_partials, out);
}